// Round 3
// baseline (376.478 us; speedup 1.0000x reference)
//
#include <hip/hip_runtime.h>
#include <cstdint>
#include <cstddef>

#define NEG_C 1000000000000.0f

typedef __bf16 bf16x8 __attribute__((ext_vector_type(8)));
typedef float f32x4 __attribute__((ext_vector_type(4)));

union Frag {
    int4 i;
    bf16x8 b;
};

__device__ __forceinline__ unsigned short f32_to_bf16_rne(float f) {
    unsigned int u = __float_as_uint(f);
    u += 0x7fffu + ((u >> 16) & 1u);
    return (unsigned short)(u >> 16);
}

// Async global->LDS DMA, 16 B per lane. LDS dest is wave-uniform base;
// lane i's data lands at base + i*16 (m97/m104 semantics).
// C-style casts: static_cast rejects the const+addrspace reinterpret.
__device__ __forceinline__ void async_copy16(const void* g, void* l) {
    __builtin_amdgcn_global_load_lds(
        (const __attribute__((address_space(1))) unsigned int*)(uintptr_t)g,
        (__attribute__((address_space(3))) unsigned int*)(uintptr_t)l,
        16, 0, 0);
}

// ---------------------------------------------------------------- convert
// hidden f32 [16*512*768] -> bf16, vectorized (float4 -> ushort4)
__global__ void convert_hidden_kernel(const float* __restrict__ src,
                                      unsigned short* __restrict__ dst, int n4) {
    int idx = blockIdx.x * blockDim.x + threadIdx.x;
    if (idx >= n4) return;
    float4 v = ((const float4*)src)[idx];
    ushort4 o;
    o.x = f32_to_bf16_rne(v.x);
    o.y = f32_to_bf16_rne(v.y);
    o.z = f32_to_bf16_rne(v.z);
    o.w = f32_to_bf16_rne(v.w);
    ((ushort4*)dst)[idx] = o;
}

// ---------------------------------------------------------------- W transpose
// W f32 [768][1152] -> WT bf16 [1152][768]
__global__ void transpose_w_kernel(const float* __restrict__ W,
                                   unsigned short* __restrict__ WT) {
    __shared__ unsigned short tile[32][33];
    int bx = blockIdx.x;              // n-tile: 0..35
    int by = blockIdx.y;              // k-tile: 0..23
    int x = threadIdx.x & 31;
    int y0 = threadIdx.x >> 5;        // 0..7
#pragma unroll
    for (int yy = 0; yy < 32; yy += 8) {
        int k = by * 32 + y0 + yy;
        int n = bx * 32 + x;
        tile[y0 + yy][x] = f32_to_bf16_rne(W[(size_t)k * 1152 + n]);
    }
    __syncthreads();
#pragma unroll
    for (int yy = 0; yy < 32; yy += 8) {
        int n = bx * 32 + y0 + yy;
        int k = by * 32 + x;
        WT[(size_t)n * 768 + k] = tile[x][y0 + yy];
    }
}

// ---------------------------------------------------------------- GEMM1 + RoPE
// proj[8192][1152](bf16) = rope(Ah[8192][768] @ W + bias)
// 128x128 tile, BK=64, global_load_lds(16B) staging with XOR chunk swizzle:
//   row r (128B = 8 chunks of 16B), logical chunk g stored at slot g^(r&7).
//   DMA: lane L of call q writes LDS chunk (wave*4+q)*64+L -> contiguous.
//   Frag ds_read_b128: banks 2-way only (free).
__global__ __launch_bounds__(256, 2) void gemm1_kernel(
    const unsigned short* __restrict__ Ah, const unsigned short* __restrict__ WT,
    const float* __restrict__ bias, unsigned short* __restrict__ proj) {
    const int K = 768, N = 1152;
    __shared__ unsigned short As[128 * 64];   // 16 KB, swizzled
    __shared__ unsigned short Bs[128 * 64];   // 16 KB, swizzled
    int tid = threadIdx.x;
    int lane = tid & 63;
    int wave = tid >> 6;
    int bm = blockIdx.x * 128;
    int bn = blockIdx.y * 128;                // = t*128
    int wm = (wave & 1) * 64;
    int wn = (wave >> 1) * 64;
    int col_l = lane & 15;
    int qg = lane >> 4;                       // quad-group 0..3

    int c0 = wave * 4 * 64 + lane;            // this wave's call-0 chunk id
    f32x4 acc[4][4] = {};

    for (int k0 = 0; k0 < K; k0 += 64) {
        __syncthreads();
#pragma unroll
        for (int q = 0; q < 4; ++q) {
            int c = c0 + q * 64;              // 0..1023
            int r = c >> 3;
            int g = (c & 7) ^ (r & 7);
            async_copy16(Ah + (size_t)(bm + r) * K + k0 + g * 8,
                         As + (size_t)(wave * 4 + q) * 512);
            async_copy16(WT + (size_t)(bn + r) * K + k0 + g * 8,
                         Bs + (size_t)(wave * 4 + q) * 512);
        }
        __syncthreads();                      // compiler drains vmcnt here
        Frag a[2][4], bfr[2][4];
#pragma unroll
        for (int ks = 0; ks < 2; ++ks) {
            int g = ks * 4 + qg;
#pragma unroll
            for (int i = 0; i < 4; ++i) {
                int ra = wm + i * 16 + col_l;
                int rb = wn + i * 16 + col_l;
                a[ks][i].i   = *(const int4*)(As + ra * 64 + ((g ^ (ra & 7)) * 8));
                bfr[ks][i].i = *(const int4*)(Bs + rb * 64 + ((g ^ (rb & 7)) * 8));
            }
        }
#pragma unroll
        for (int ks = 0; ks < 2; ++ks)
#pragma unroll
            for (int i = 0; i < 4; ++i)
#pragma unroll
                for (int j = 0; j < 4; ++j)
                    acc[i][j] = __builtin_amdgcn_mfma_f32_16x16x32_bf16(
                        a[ks][i].b, bfr[ks][j].b, acc[i][j], 0, 0, 0);
    }

    // epilogue: +bias, RoPE (pair partner = lane^1), -> bf16
    int row_q = qg * 4;
#pragma unroll
    for (int j = 0; j < 4; ++j) {
        int cn = wn + j * 16 + col_l;         // 0..127 within this t-block
        int gn = bn + cn;
        int pair = (cn >> 1) & 31;
        int odd = cn & 1;
        float inv = exp2f(-0.41524101186091903f * (float)pair);
        float bb = bias[gn];
#pragma unroll
        for (int i = 0; i < 4; ++i) {
#pragma unroll
            for (int r = 0; r < 4; ++r) {
                int gm = bm + wm + i * 16 + row_q + r;
                float v = acc[i][j][r] + bb;
                float p = __shfl_xor(v, 1, 64);   // partner col (has own bias)
                float ang = (float)(gm & 511) * inv;
                float sn, cs;
                sincosf(ang, &sn, &cs);
                float o = odd ? (v * cs + p * sn) : (v * cs - p * sn);
                proj[(size_t)gm * N + gn] = f32_to_bf16_rne(o);
            }
        }
    }
}

// ---------------------------------------------------------------- GEMM2 + mask
// out[b][t][m][n] = (q.k * pm[b,n] - (1-pm)*NEG - (m>n)*NEG)/8
// Same DMA+swizzle staging; K=64 (one shot). Fully-masked tiles fast-path.
__global__ __launch_bounds__(256, 2) void gemm2_kernel(
    const unsigned short* __restrict__ proj, const int* __restrict__ mask,
    float* __restrict__ out) {
    __shared__ unsigned short Qs[128 * 64];   // rows of 64 bf16 = 8 chunks, swizzled
    __shared__ unsigned short Ks[128 * 64];
    int bid = blockIdx.x;          // 144*16
    int batch = bid >> 4;
    int tl = bid & 15;
    int tm = tl >> 2, tn = tl & 3;
    int b = batch / 9, t = batch - b * 9;
    int tid = threadIdx.x, lane = tid & 63, wave = tid >> 6;
    int wm = (wave & 1) * 64, wn = (wave >> 1) * 64;
    int col_l = lane & 15;
    int qg = lane >> 4;
    size_t out_base = ((size_t)b * 9 + t) * 512 * 512;

    if (tm > tn) {
        // whole tile strictly below diagonal: |L|/8 error << threshold
#pragma unroll 4
        for (int r = 0; r < 128; r += 8) {
            int row = r + (tid >> 5);
            int c4 = (tid & 31) * 4;
            int gm = tm * 128 + row;
            int gn = tn * 128 + c4;
            float4 v;
#pragma unroll
            for (int q = 0; q < 4; ++q) {
                float pm = (float)mask[b * 512 + gn + q];
                ((float*)&v)[q] = (-(1.0f - pm) * NEG_C - NEG_C) * 0.125f;
            }
            *(float4*)(out + out_base + (size_t)gm * 512 + gn) = v;
        }
        return;
    }

    // DMA stage: Q rows (tm tile, d 0..63) and K rows (tn tile, d 64..127)
    const unsigned short* qbase = proj + (((size_t)(b * 512 + tm * 128) * 9) + t) * 128;
    const unsigned short* kbase = proj + (((size_t)(b * 512 + tn * 128) * 9) + t) * 128 + 64;
#pragma unroll
    for (int q = 0; q < 4; ++q) {
        int c = (wave * 4 + q) * 64 + lane;   // 0..1023
        int r = c >> 3;
        int g = (c & 7) ^ (r & 7);
        async_copy16(qbase + (size_t)r * 1152 + g * 8,
                     Qs + (size_t)(wave * 4 + q) * 512);
        async_copy16(kbase + (size_t)r * 1152 + g * 8,
                     Ks + (size_t)(wave * 4 + q) * 512);
    }
    __syncthreads();

    f32x4 acc[4][4] = {};
#pragma unroll
    for (int ks = 0; ks < 2; ++ks) {
        Frag a[4], bfr[4];
        int g = ks * 4 + qg;
#pragma unroll
        for (int i = 0; i < 4; ++i) {
            int ra = wm + i * 16 + col_l;
            int rb = wn + i * 16 + col_l;
            a[i].i   = *(const int4*)(Qs + ra * 64 + ((g ^ (ra & 7)) * 8));
            bfr[i].i = *(const int4*)(Ks + rb * 64 + ((g ^ (rb & 7)) * 8));
        }
#pragma unroll
        for (int i = 0; i < 4; ++i)
#pragma unroll
            for (int j = 0; j < 4; ++j)
                acc[i][j] = __builtin_amdgcn_mfma_f32_16x16x32_bf16(
                    a[i].b, bfr[j].b, acc[i][j], 0, 0, 0);
    }

    int row_q = qg * 4;
#pragma unroll
    for (int i = 0; i < 4; ++i) {
#pragma unroll
        for (int j = 0; j < 4; ++j) {
            int gn = tn * 128 + wn + j * 16 + col_l;
            float pm = (float)mask[b * 512 + gn];
#pragma unroll
            for (int r = 0; r < 4; ++r) {
                int gm = tm * 128 + wm + i * 16 + row_q + r;
                float v = acc[i][j][r] * pm - (1.0f - pm) * NEG_C;
                if (gm > gn) v -= NEG_C;
                out[out_base + (size_t)gm * 512 + gn] = v * 0.125f;
            }
        }
    }
}

// ---------------------------------------------------------------- launch
extern "C" void kernel_launch(void* const* d_in, const int* in_sizes, int n_in,
                              void* d_out, int out_size, void* d_ws, size_t ws_size,
                              hipStream_t stream) {
    const float* hidden = (const float*)d_in[0];   // [16][512][768]
    const float* W      = (const float*)d_in[1];   // [768][1152]
    const float* bias   = (const float*)d_in[2];   // [1152]
    const int*   mask   = (const int*)d_in[3];     // [16][512]
    float* out = (float*)d_out;                    // [16][9][512][512]

    char* ws = (char*)d_ws;
    unsigned short* Ah   = (unsigned short*)(ws);              // 8192*768  bf16
    unsigned short* WT   = (unsigned short*)(ws + 12582912);   // 1152*768  bf16
    unsigned short* proj = (unsigned short*)(ws + 14352384);   // 8192*1152 bf16

    convert_hidden_kernel<<<6144, 256, 0, stream>>>(hidden, Ah, 1572864);
    dim3 gt(36, 24);
    transpose_w_kernel<<<gt, 256, 0, stream>>>(W, WT);
    dim3 g1(64, 9);
    gemm1_kernel<<<g1, 256, 0, stream>>>(Ah, WT, bias, proj);
    gemm2_kernel<<<2304, 256, 0, stream>>>(proj, mask, out);
}

// Round 4
// 220.161 us; speedup vs baseline: 1.7100x; 1.7100x over previous
//
#include <hip/hip_runtime.h>
#include <cstdint>
#include <cstddef>

#define NEG_C 1000000000000.0f

typedef __bf16 bf16x8 __attribute__((ext_vector_type(8)));
typedef float f32x4 __attribute__((ext_vector_type(4)));

union Frag {
    int4 i;
    bf16x8 b;
};

__device__ __forceinline__ unsigned short f32_to_bf16_rne(float f) {
    unsigned int u = __float_as_uint(f);
    u += 0x7fffu + ((u >> 16) & 1u);
    return (unsigned short)(u >> 16);
}

// Async global->LDS DMA, 16 B per lane. LDS dest is wave-uniform base;
// lane i's data lands at base + i*16 (m97/m104 semantics).
__device__ __forceinline__ void async_copy16(const void* g, void* l) {
    __builtin_amdgcn_global_load_lds(
        (const __attribute__((address_space(1))) unsigned int*)(uintptr_t)g,
        (__attribute__((address_space(3))) unsigned int*)(uintptr_t)l,
        16, 0, 0);
}

// ---------------------------------------------------------------- convert
__global__ void convert_hidden_kernel(const float* __restrict__ src,
                                      unsigned short* __restrict__ dst, int n4) {
    int idx = blockIdx.x * blockDim.x + threadIdx.x;
    if (idx >= n4) return;
    float4 v = ((const float4*)src)[idx];
    ushort4 o;
    o.x = f32_to_bf16_rne(v.x);
    o.y = f32_to_bf16_rne(v.y);
    o.z = f32_to_bf16_rne(v.z);
    o.w = f32_to_bf16_rne(v.w);
    ((ushort4*)dst)[idx] = o;
}

// ---------------------------------------------------------------- W transpose
__global__ void transpose_w_kernel(const float* __restrict__ W,
                                   unsigned short* __restrict__ WT) {
    __shared__ unsigned short tile[32][33];
    int bx = blockIdx.x;              // n-tile: 0..35
    int by = blockIdx.y;              // k-tile: 0..23
    int x = threadIdx.x & 31;
    int y0 = threadIdx.x >> 5;        // 0..7
#pragma unroll
    for (int yy = 0; yy < 32; yy += 8) {
        int k = by * 32 + y0 + yy;
        int n = bx * 32 + x;
        tile[y0 + yy][x] = f32_to_bf16_rne(W[(size_t)k * 1152 + n]);
    }
    __syncthreads();
#pragma unroll
    for (int yy = 0; yy < 32; yy += 8) {
        int n = bx * 32 + y0 + yy;
        int k = by * 32 + x;
        WT[(size_t)n * 768 + k] = tile[x][y0 + yy];
    }
}

// ---------------------------------------------------------------- GEMM1 + RoPE
// proj[8192][1152](bf16) = rope(Ah[8192][768] @ W + bias)
// 128x128 tile, BK=64, global_load_lds(16B) + XOR chunk swizzle (2-way banks).
// R3 spill fix: sincosf -> __sinf/__cosf (no lib call in epilogue),
// frags loaded per-ks (a[4]/b[4], not a[2][4]).
__global__ __launch_bounds__(256, 2) void gemm1_kernel(
    const unsigned short* __restrict__ Ah, const unsigned short* __restrict__ WT,
    const float* __restrict__ bias, unsigned short* __restrict__ proj) {
    const int K = 768, N = 1152;
    __shared__ unsigned short As[128 * 64];   // 16 KB, swizzled
    __shared__ unsigned short Bs[128 * 64];   // 16 KB, swizzled
    int tid = threadIdx.x;
    int lane = tid & 63;
    int wave = tid >> 6;
    int bm = blockIdx.x * 128;
    int bn = blockIdx.y * 128;                // = t*128
    int wm = (wave & 1) * 64;
    int wn = (wave >> 1) * 64;
    int col_l = lane & 15;
    int qg = lane >> 4;                       // quad-group 0..3

    int c0 = wave * 4 * 64 + lane;            // this wave's call-0 chunk id
    f32x4 acc[4][4] = {};

    for (int k0 = 0; k0 < K; k0 += 64) {
        __syncthreads();
#pragma unroll
        for (int q = 0; q < 4; ++q) {
            int c = c0 + q * 64;              // 0..1023
            int r = c >> 3;
            int g = (c & 7) ^ (r & 7);
            async_copy16(Ah + (size_t)(bm + r) * K + k0 + g * 8,
                         As + (size_t)(wave * 4 + q) * 512);
            async_copy16(WT + (size_t)(bn + r) * K + k0 + g * 8,
                         Bs + (size_t)(wave * 4 + q) * 512);
        }
        __syncthreads();                      // drains vmcnt
#pragma unroll
        for (int ks = 0; ks < 2; ++ks) {
            Frag a[4], bfr[4];
            int g = ks * 4 + qg;
#pragma unroll
            for (int i = 0; i < 4; ++i) {
                int ra = wm + i * 16 + col_l;
                int rb = wn + i * 16 + col_l;
                a[i].i   = *(const int4*)(As + ra * 64 + ((g ^ (ra & 7)) * 8));
                bfr[i].i = *(const int4*)(Bs + rb * 64 + ((g ^ (rb & 7)) * 8));
            }
#pragma unroll
            for (int i = 0; i < 4; ++i)
#pragma unroll
                for (int j = 0; j < 4; ++j)
                    acc[i][j] = __builtin_amdgcn_mfma_f32_16x16x32_bf16(
                        a[i].b, bfr[j].b, acc[i][j], 0, 0, 0);
        }
    }

    // epilogue: +bias, RoPE (pair partner = lane^1), -> bf16
    int row_q = qg * 4;
#pragma unroll
    for (int j = 0; j < 4; ++j) {
        int cn = wn + j * 16 + col_l;         // 0..127 within this t-block
        int gn = bn + cn;
        int pair = (cn >> 1) & 31;
        int odd = cn & 1;
        float inv = exp2f(-0.41524101186091903f * (float)pair);
        float bb = bias[gn];
#pragma unroll
        for (int i = 0; i < 4; ++i) {
#pragma unroll
            for (int r = 0; r < 4; ++r) {
                int gm = bm + wm + i * 16 + row_q + r;
                float v = acc[i][j][r] + bb;
                float p = __shfl_xor(v, 1, 64);   // partner col (has own bias)
                float ang = (float)(gm & 511) * inv;
                float sn = __sinf(ang);           // inline v_sin_f32 path
                float cs = __cosf(ang);
                float o = odd ? (v * cs + p * sn) : (v * cs - p * sn);
                proj[(size_t)gm * N + gn] = f32_to_bf16_rne(o);
            }
        }
    }
}

// ---------------------------------------------------------------- GEMM2 + mask
// out[b][t][m][n] = (q.k * pm[b,n] - (1-pm)*NEG - (m>n)*NEG)/8
__global__ __launch_bounds__(256, 2) void gemm2_kernel(
    const unsigned short* __restrict__ proj, const int* __restrict__ mask,
    float* __restrict__ out) {
    __shared__ unsigned short Qs[128 * 64];   // swizzled
    __shared__ unsigned short Ks[128 * 64];
    int bid = blockIdx.x;          // 144*16
    int batch = bid >> 4;
    int tl = bid & 15;
    int tm = tl >> 2, tn = tl & 3;
    int b = batch / 9, t = batch - b * 9;
    int tid = threadIdx.x, lane = tid & 63, wave = tid >> 6;
    int wm = (wave & 1) * 64, wn = (wave >> 1) * 64;
    int col_l = lane & 15;
    int qg = lane >> 4;
    size_t out_base = ((size_t)b * 9 + t) * 512 * 512;

    if (tm > tn) {
        // whole tile strictly below diagonal: |L|/8 error << threshold
#pragma unroll 4
        for (int r = 0; r < 128; r += 8) {
            int row = r + (tid >> 5);
            int c4 = (tid & 31) * 4;
            int gm = tm * 128 + row;
            int gn = tn * 128 + c4;
            float4 v;
#pragma unroll
            for (int q = 0; q < 4; ++q) {
                float pm = (float)mask[b * 512 + gn + q];
                ((float*)&v)[q] = (-(1.0f - pm) * NEG_C - NEG_C) * 0.125f;
            }
            *(float4*)(out + out_base + (size_t)gm * 512 + gn) = v;
        }
        return;
    }

    const unsigned short* qbase = proj + (((size_t)(b * 512 + tm * 128) * 9) + t) * 128;
    const unsigned short* kbase = proj + (((size_t)(b * 512 + tn * 128) * 9) + t) * 128 + 64;
#pragma unroll
    for (int q = 0; q < 4; ++q) {
        int c = (wave * 4 + q) * 64 + lane;   // 0..1023
        int r = c >> 3;
        int g = (c & 7) ^ (r & 7);
        async_copy16(qbase + (size_t)r * 1152 + g * 8,
                     Qs + (size_t)(wave * 4 + q) * 512);
        async_copy16(kbase + (size_t)r * 1152 + g * 8,
                     Ks + (size_t)(wave * 4 + q) * 512);
    }
    __syncthreads();

    f32x4 acc[4][4] = {};
#pragma unroll
    for (int ks = 0; ks < 2; ++ks) {
        Frag a[4], bfr[4];
        int g = ks * 4 + qg;
#pragma unroll
        for (int i = 0; i < 4; ++i) {
            int ra = wm + i * 16 + col_l;
            int rb = wn + i * 16 + col_l;
            a[i].i   = *(const int4*)(Qs + ra * 64 + ((g ^ (ra & 7)) * 8));
            bfr[i].i = *(const int4*)(Ks + rb * 64 + ((g ^ (rb & 7)) * 8));
        }
#pragma unroll
        for (int i = 0; i < 4; ++i)
#pragma unroll
            for (int j = 0; j < 4; ++j)
                acc[i][j] = __builtin_amdgcn_mfma_f32_16x16x32_bf16(
                    a[i].b, bfr[j].b, acc[i][j], 0, 0, 0);
    }

    int row_q = qg * 4;
#pragma unroll
    for (int i = 0; i < 4; ++i) {
#pragma unroll
        for (int j = 0; j < 4; ++j) {
            int gn = tn * 128 + wn + j * 16 + col_l;
            float pm = (float)mask[b * 512 + gn];
#pragma unroll
            for (int r = 0; r < 4; ++r) {
                int gm = tm * 128 + wm + i * 16 + row_q + r;
                float v = acc[i][j][r] * pm - (1.0f - pm) * NEG_C;
                if (gm > gn) v -= NEG_C;
                out[out_base + (size_t)gm * 512 + gn] = v * 0.125f;
            }
        }
    }
}

// ---------------------------------------------------------------- launch
extern "C" void kernel_launch(void* const* d_in, const int* in_sizes, int n_in,
                              void* d_out, int out_size, void* d_ws, size_t ws_size,
                              hipStream_t stream) {
    const float* hidden = (const float*)d_in[0];   // [16][512][768]
    const float* W      = (const float*)d_in[1];   // [768][1152]
    const float* bias   = (const float*)d_in[2];   // [1152]
    const int*   mask   = (const int*)d_in[3];     // [16][512]
    float* out = (float*)d_out;                    // [16][9][512][512]

    char* ws = (char*)d_ws;
    unsigned short* Ah   = (unsigned short*)(ws);              // 8192*768  bf16
    unsigned short* WT   = (unsigned short*)(ws + 12582912);   // 1152*768  bf16
    unsigned short* proj = (unsigned short*)(ws + 14352384);   // 8192*1152 bf16

    convert_hidden_kernel<<<6144, 256, 0, stream>>>(hidden, Ah, 1572864);
    dim3 gt(36, 24);
    transpose_w_kernel<<<gt, 256, 0, stream>>>(W, WT);
    dim3 g1(64, 9);
    gemm1_kernel<<<g1, 256, 0, stream>>>(Ah, WT, bias, proj);
    gemm2_kernel<<<2304, 256, 0, stream>>>(proj, mask, out);
}

// Round 6
// 218.985 us; speedup vs baseline: 1.7192x; 1.0054x over previous
//
#include <hip/hip_runtime.h>
#include <cstdint>
#include <cstddef>

#define NEG_C 1000000000000.0f

typedef __bf16 bf16x8 __attribute__((ext_vector_type(8)));
typedef float f32x4 __attribute__((ext_vector_type(4)));

union Frag {
    int4 i;
    bf16x8 b;
};

__device__ __forceinline__ unsigned short f32_to_bf16_rne(float f) {
    unsigned int u = __float_as_uint(f);
    u += 0x7fffu + ((u >> 16) & 1u);
    return (unsigned short)(u >> 16);
}

// Async global->LDS DMA, 16 B per lane (m97/m104 semantics).
__device__ __forceinline__ void async_copy16(const void* g, void* l) {
    __builtin_amdgcn_global_load_lds(
        (const __attribute__((address_space(1))) unsigned int*)(uintptr_t)g,
        (__attribute__((address_space(3))) unsigned int*)(uintptr_t)l,
        16, 0, 0);
}

// ---------------------------------------------------------------- convert
__global__ void convert_hidden_kernel(const float* __restrict__ src,
                                      unsigned short* __restrict__ dst, int n4) {
    int idx = blockIdx.x * blockDim.x + threadIdx.x;
    if (idx >= n4) return;
    float4 v = ((const float4*)src)[idx];
    ushort4 o;
    o.x = f32_to_bf16_rne(v.x);
    o.y = f32_to_bf16_rne(v.y);
    o.z = f32_to_bf16_rne(v.z);
    o.w = f32_to_bf16_rne(v.w);
    ((ushort4*)dst)[idx] = o;
}

// ---------------------------------------------------------------- W transpose
__global__ void transpose_w_kernel(const float* __restrict__ W,
                                   unsigned short* __restrict__ WT) {
    __shared__ unsigned short tile[32][33];
    int bx = blockIdx.x;              // n-tile: 0..35
    int by = blockIdx.y;              // k-tile: 0..23
    int x = threadIdx.x & 31;
    int y0 = threadIdx.x >> 5;        // 0..7
#pragma unroll
    for (int yy = 0; yy < 32; yy += 8) {
        int k = by * 32 + y0 + yy;
        int n = bx * 32 + x;
        tile[y0 + yy][x] = f32_to_bf16_rne(W[(size_t)k * 1152 + n]);
    }
    __syncthreads();
#pragma unroll
    for (int yy = 0; yy < 32; yy += 8) {
        int n = bx * 32 + y0 + yy;
        int k = by * 32 + x;
        WT[(size_t)n * 768 + k] = tile[x][y0 + yy];
    }
}

// ---------------------------------------------------------------- GEMM1 + RoPE
// proj[8192][1152](bf16) = rope(Ah[8192][768] @ W + bias)
// Operand-swapped MFMA: acc rows = n (WT), cols = m (Ah)  ->  each lane's
// f32x4 = 4 consecutive n columns => ushort4 stores, in-lane RoPE pairs.
__global__ __launch_bounds__(256, 2) void gemm1_kernel(
    const unsigned short* __restrict__ Ah, const unsigned short* __restrict__ WT,
    const float* __restrict__ bias, unsigned short* __restrict__ proj) {
    const int K = 768, N = 1152;
    __shared__ unsigned short As[128 * 64];   // Ah rows (m), swizzled
    __shared__ unsigned short Bs[128 * 64];   // WT rows (n), swizzled
    int tid = threadIdx.x;
    int lane = tid & 63;
    int wave = tid >> 6;
    int bm = blockIdx.x * 128;
    int bn = blockIdx.y * 128;                // = t*128
    int wm = (wave & 1) * 64;
    int wn = (wave >> 1) * 64;
    int col_l = lane & 15;
    int qg = lane >> 4;                       // quad-group 0..3

    int c0 = wave * 4 * 64 + lane;
    f32x4 acc[4][4] = {};                     // [i:n-block][j:m-block]

    for (int k0 = 0; k0 < K; k0 += 64) {
        __syncthreads();
#pragma unroll
        for (int q = 0; q < 4; ++q) {
            int c = c0 + q * 64;              // 0..1023
            int r = c >> 3;
            int g = (c & 7) ^ (r & 7);
            async_copy16(Ah + (size_t)(bm + r) * K + k0 + g * 8,
                         As + (size_t)(wave * 4 + q) * 512);
            async_copy16(WT + (size_t)(bn + r) * K + k0 + g * 8,
                         Bs + (size_t)(wave * 4 + q) * 512);
        }
        __syncthreads();                      // drains vmcnt
#pragma unroll
        for (int ks = 0; ks < 2; ++ks) {
            Frag qf[4], kf[4];
            int g = ks * 4 + qg;
#pragma unroll
            for (int i = 0; i < 4; ++i) {
                int rm = wm + i * 16 + col_l;   // m rows (B-operand)
                int rn = wn + i * 16 + col_l;   // n rows (A-operand)
                qf[i].i = *(const int4*)(As + rm * 64 + ((g ^ (rm & 7)) * 8));
                kf[i].i = *(const int4*)(Bs + rn * 64 + ((g ^ (rn & 7)) * 8));
            }
#pragma unroll
            for (int i = 0; i < 4; ++i)
#pragma unroll
                for (int j = 0; j < 4; ++j)
                    acc[i][j] = __builtin_amdgcn_mfma_f32_16x16x32_bf16(
                        kf[i].b, qf[j].b, acc[i][j], 0, 0, 0);
        }
    }

    // epilogue: +bias, RoPE (pairs in-lane: cols cn0..cn0+3), -> ushort4
#pragma unroll
    for (int i = 0; i < 4; ++i) {
        int cn0 = wn + i * 16 + qg * 4;       // 0..124, %4==0 (within t-block)
        int gn0 = bn + cn0;
        float4 bb = *(const float4*)(bias + gn0);
        int p0 = cn0 >> 1;                    // pair indices p0, p0+1
        float inv0 = exp2f(-0.41524101186091903f * (float)p0);
        float inv1 = exp2f(-0.41524101186091903f * (float)(p0 + 1));
#pragma unroll
        for (int j = 0; j < 4; ++j) {
            int gm = bm + wm + j * 16 + col_l;
            float s = (float)(gm & 511);
            float a0 = s * inv0, a1 = s * inv1;
            float sn0 = __sinf(a0), cs0 = __cosf(a0);
            float sn1 = __sinf(a1), cs1 = __cosf(a1);
            float v0 = acc[i][j][0] + bb.x;
            float v1 = acc[i][j][1] + bb.y;
            float v2 = acc[i][j][2] + bb.z;
            float v3 = acc[i][j][3] + bb.w;
            ushort4 o;
            o.x = f32_to_bf16_rne(v0 * cs0 - v1 * sn0);
            o.y = f32_to_bf16_rne(v1 * cs0 + v0 * sn0);
            o.z = f32_to_bf16_rne(v2 * cs1 - v3 * sn1);
            o.w = f32_to_bf16_rne(v3 * cs1 + v2 * sn1);
            *(ushort4*)(proj + (size_t)gm * N + gn0) = o;
        }
    }
}

// ---------------------------------------------------------------- GEMM2 + mask
// out[b][t][m][n] = (q.k * pm[b,n] - (1-pm)*NEG - (m>n)*NEG)/8
// Operand-swapped: lane's f32x4 = 4 consecutive n => f32x4 nt stores.
__global__ __launch_bounds__(256, 2) void gemm2_kernel(
    const unsigned short* __restrict__ proj, const int* __restrict__ mask,
    float* __restrict__ out) {
    __shared__ unsigned short Qs[128 * 64];   // swizzled
    __shared__ unsigned short Ks[128 * 64];
    int bid = blockIdx.x;          // 144*16
    int batch = bid >> 4;
    int tl = bid & 15;
    int tm = tl >> 2, tn = tl & 3;
    int b = batch / 9, t = batch - b * 9;
    int tid = threadIdx.x, lane = tid & 63, wave = tid >> 6;
    int wm = (wave & 1) * 64, wn = (wave >> 1) * 64;
    int col_l = lane & 15;
    int qg = lane >> 4;
    size_t out_base = ((size_t)b * 9 + t) * 512 * 512;

    if (tm > tn) {
        // whole tile strictly below diagonal: |L|/8 error << threshold
#pragma unroll 4
        for (int r = 0; r < 128; r += 8) {
            int row = r + (tid >> 5);
            int c4 = (tid & 31) * 4;
            int gm = tm * 128 + row;
            int gn = tn * 128 + c4;
            int4 mi = *(const int4*)(mask + b * 512 + gn);
            f32x4 v;
            v[0] = (-(1.0f - (float)mi.x) * NEG_C - NEG_C) * 0.125f;
            v[1] = (-(1.0f - (float)mi.y) * NEG_C - NEG_C) * 0.125f;
            v[2] = (-(1.0f - (float)mi.z) * NEG_C - NEG_C) * 0.125f;
            v[3] = (-(1.0f - (float)mi.w) * NEG_C - NEG_C) * 0.125f;
            __builtin_nontemporal_store(v, (f32x4*)(out + out_base + (size_t)gm * 512 + gn));
        }
        return;
    }

    const unsigned short* qbase = proj + (((size_t)(b * 512 + tm * 128) * 9) + t) * 128;
    const unsigned short* kbase = proj + (((size_t)(b * 512 + tn * 128) * 9) + t) * 128 + 64;
#pragma unroll
    for (int q = 0; q < 4; ++q) {
        int c = (wave * 4 + q) * 64 + lane;   // 0..1023
        int r = c >> 3;
        int g = (c & 7) ^ (r & 7);
        async_copy16(qbase + (size_t)r * 1152 + g * 8,
                     Qs + (size_t)(wave * 4 + q) * 512);
        async_copy16(kbase + (size_t)r * 1152 + g * 8,
                     Ks + (size_t)(wave * 4 + q) * 512);
    }
    __syncthreads();

    f32x4 acc[4][4] = {};                     // [i:n-block][j:m-block]
#pragma unroll
    for (int ks = 0; ks < 2; ++ks) {
        Frag qf[4], kf[4];
        int g = ks * 4 + qg;
#pragma unroll
        for (int i = 0; i < 4; ++i) {
            int rm = wm + i * 16 + col_l;
            int rn = wn + i * 16 + col_l;
            qf[i].i = *(const int4*)(Qs + rm * 64 + ((g ^ (rm & 7)) * 8));
            kf[i].i = *(const int4*)(Ks + rn * 64 + ((g ^ (rn & 7)) * 8));
        }
#pragma unroll
        for (int i = 0; i < 4; ++i)
#pragma unroll
            for (int j = 0; j < 4; ++j)
                acc[i][j] = __builtin_amdgcn_mfma_f32_16x16x32_bf16(
                    kf[i].b, qf[j].b, acc[i][j], 0, 0, 0);
    }

#pragma unroll
    for (int i = 0; i < 4; ++i) {
        int gn0 = tn * 128 + wn + i * 16 + qg * 4;   // %4==0
        int4 mi = *(const int4*)(mask + b * 512 + gn0);
#pragma unroll
        for (int j = 0; j < 4; ++j) {
            int gm = tm * 128 + wm + j * 16 + col_l;
            f32x4 v;
#pragma unroll
            for (int r = 0; r < 4; ++r) {
                float pm = (float)((&mi.x)[r]);
                float x = acc[i][j][r] * pm - (1.0f - pm) * NEG_C;
                if (gm > gn0 + r) x -= NEG_C;
                v[r] = x * 0.125f;
            }
            __builtin_nontemporal_store(v, (f32x4*)(out + out_base + (size_t)gm * 512 + gn0));
        }
    }
}

// ---------------------------------------------------------------- launch
extern "C" void kernel_launch(void* const* d_in, const int* in_sizes, int n_in,
                              void* d_out, int out_size, void* d_ws, size_t ws_size,
                              hipStream_t stream) {
    const float* hidden = (const float*)d_in[0];   // [16][512][768]
    const float* W      = (const float*)d_in[1];   // [768][1152]
    const float* bias   = (const float*)d_in[2];   // [1152]
    const int*   mask   = (const int*)d_in[3];     // [16][512]
    float* out = (float*)d_out;                    // [16][9][512][512]

    char* ws = (char*)d_ws;
    unsigned short* Ah   = (unsigned short*)(ws);              // 8192*768  bf16
    unsigned short* WT   = (unsigned short*)(ws + 12582912);   // 1152*768  bf16
    unsigned short* proj = (unsigned short*)(ws + 14352384);   // 8192*1152 bf16

    convert_hidden_kernel<<<6144, 256, 0, stream>>>(hidden, Ah, 1572864);
    dim3 gt(36, 24);
    transpose_w_kernel<<<gt, 256, 0, stream>>>(W, WT);
    dim3 g1(64, 9);
    gemm1_kernel<<<g1, 256, 0, stream>>>(Ah, WT, bias, proj);
    gemm2_kernel<<<2304, 256, 0, stream>>>(proj, mask, out);
}

// Round 7
// 214.411 us; speedup vs baseline: 1.7559x; 1.0213x over previous
//
#include <hip/hip_runtime.h>
#include <cstdint>
#include <cstddef>

#define NEG_C 1000000000000.0f

typedef __bf16 bf16x8 __attribute__((ext_vector_type(8)));
typedef float f32x4 __attribute__((ext_vector_type(4)));

union Frag {
    int4 i;
    bf16x8 b;
};

__device__ __forceinline__ unsigned short f32_to_bf16_rne(float f) {
    unsigned int u = __float_as_uint(f);
    u += 0x7fffu + ((u >> 16) & 1u);
    return (unsigned short)(u >> 16);
}

// Async global->LDS DMA, 16 B per lane (m97/m104 semantics).
__device__ __forceinline__ void async_copy16(const void* g, void* l) {
    __builtin_amdgcn_global_load_lds(
        (const __attribute__((address_space(1))) unsigned int*)(uintptr_t)g,
        (__attribute__((address_space(3))) unsigned int*)(uintptr_t)l,
        16, 0, 0);
}

// ---------------------------------------------------------------- prep
// blocks [0,864): transpose W f32[768][1152] -> WT bf16[1152][768]
// blocks [864,7008): convert hidden f32 -> bf16 (float4->ushort4)
__global__ void prep_kernel(const float* __restrict__ W,
                            unsigned short* __restrict__ WT,
                            const float* __restrict__ hidden,
                            unsigned short* __restrict__ Ah) {
    __shared__ unsigned short tile[32][33];
    int blk = blockIdx.x;
    if (blk < 864) {
        int bx = blk % 36;                // n-tile
        int by = blk / 36;                // k-tile
        int x = threadIdx.x & 31;
        int y0 = threadIdx.x >> 5;        // 0..7
#pragma unroll
        for (int yy = 0; yy < 32; yy += 8) {
            int k = by * 32 + y0 + yy;
            int n = bx * 32 + x;
            tile[y0 + yy][x] = f32_to_bf16_rne(W[(size_t)k * 1152 + n]);
        }
        __syncthreads();
#pragma unroll
        for (int yy = 0; yy < 32; yy += 8) {
            int n = bx * 32 + y0 + yy;
            int k = by * 32 + x;
            WT[(size_t)n * 768 + k] = tile[x][y0 + yy];
        }
    } else {
        int idx = (blk - 864) * 256 + threadIdx.x;   // < 1572864
        float4 v = ((const float4*)hidden)[idx];
        ushort4 o;
        o.x = f32_to_bf16_rne(v.x);
        o.y = f32_to_bf16_rne(v.y);
        o.z = f32_to_bf16_rne(v.z);
        o.w = f32_to_bf16_rne(v.w);
        ((ushort4*)Ah)[idx] = o;
    }
}

// ---------------------------------------------------------------- GEMM1 + RoPE
// proj[8192][1152](bf16) = rope(Ah[8192][768] @ W + bias)
// Operand-swapped MFMA: lane's f32x4 = 4 consecutive n cols -> ushort4 stores.
// grid (9,64): t fast-varying so consecutive blocks share the A-tile (L2).
__global__ __launch_bounds__(256, 3) void gemm1_kernel(
    const unsigned short* __restrict__ Ah, const unsigned short* __restrict__ WT,
    const float* __restrict__ bias, unsigned short* __restrict__ proj) {
    const int K = 768, N = 1152;
    __shared__ unsigned short As[128 * 64];   // Ah rows (m), swizzled
    __shared__ unsigned short Bs[128 * 64];   // WT rows (n), swizzled
    int tid = threadIdx.x;
    int lane = tid & 63;
    int wave = tid >> 6;
    int bm = blockIdx.y * 128;
    int bn = blockIdx.x * 128;                // = t*128 (fast-varying)
    int wm = (wave & 1) * 64;
    int wn = (wave >> 1) * 64;
    int col_l = lane & 15;
    int qg = lane >> 4;                       // quad-group 0..3

    int c0 = wave * 4 * 64 + lane;
    f32x4 acc[4][4] = {};                     // [i:n-block][j:m-block]

    for (int k0 = 0; k0 < K; k0 += 64) {
        __syncthreads();
#pragma unroll
        for (int q = 0; q < 4; ++q) {
            int c = c0 + q * 64;              // 0..1023
            int r = c >> 3;
            int g = (c & 7) ^ (r & 7);
            async_copy16(Ah + (size_t)(bm + r) * K + k0 + g * 8,
                         As + (size_t)(wave * 4 + q) * 512);
            async_copy16(WT + (size_t)(bn + r) * K + k0 + g * 8,
                         Bs + (size_t)(wave * 4 + q) * 512);
        }
        __syncthreads();                      // drains vmcnt
#pragma unroll
        for (int ks = 0; ks < 2; ++ks) {
            Frag qf[4], kf[4];
            int g = ks * 4 + qg;
#pragma unroll
            for (int i = 0; i < 4; ++i) {
                int rm = wm + i * 16 + col_l;   // m rows (B-operand)
                int rn = wn + i * 16 + col_l;   // n rows (A-operand)
                qf[i].i = *(const int4*)(As + rm * 64 + ((g ^ (rm & 7)) * 8));
                kf[i].i = *(const int4*)(Bs + rn * 64 + ((g ^ (rn & 7)) * 8));
            }
#pragma unroll
            for (int i = 0; i < 4; ++i)
#pragma unroll
                for (int j = 0; j < 4; ++j)
                    acc[i][j] = __builtin_amdgcn_mfma_f32_16x16x32_bf16(
                        kf[i].b, qf[j].b, acc[i][j], 0, 0, 0);
        }
    }

    // epilogue: +bias, RoPE (in-lane pairs; pair idx within the q/k half!)
#pragma unroll
    for (int i = 0; i < 4; ++i) {
        int cn0 = wn + i * 16 + qg * 4;       // 0..124, %4==0 (within t-block)
        int gn0 = bn + cn0;
        float4 bb = *(const float4*)(bias + gn0);
        int p0 = (cn0 & 63) >> 1;             // pair idx 0..31 within q- or k-half
        float inv0 = exp2f(-0.41524101186091903f * (float)p0);
        float inv1 = exp2f(-0.41524101186091903f * (float)(p0 + 1));
#pragma unroll
        for (int j = 0; j < 4; ++j) {
            int gm = bm + wm + j * 16 + col_l;
            float s = (float)(gm & 511);
            float a0 = s * inv0, a1 = s * inv1;
            float sn0 = __sinf(a0), cs0 = __cosf(a0);
            float sn1 = __sinf(a1), cs1 = __cosf(a1);
            float v0 = acc[i][j][0] + bb.x;
            float v1 = acc[i][j][1] + bb.y;
            float v2 = acc[i][j][2] + bb.z;
            float v3 = acc[i][j][3] + bb.w;
            ushort4 o;
            o.x = f32_to_bf16_rne(v0 * cs0 - v1 * sn0);
            o.y = f32_to_bf16_rne(v1 * cs0 + v0 * sn0);
            o.z = f32_to_bf16_rne(v2 * cs1 - v3 * sn1);
            o.w = f32_to_bf16_rne(v3 * cs1 + v2 * sn1);
            *(ushort4*)(proj + (size_t)gm * N + gn0) = o;
        }
    }
}

// ---------------------------------------------------------------- GEMM2 + mask
// out[b][t][m][n] = (q.k * pm[b,n] - (1-pm)*NEG - (m>n)*NEG)/8
// Plain stores (L2 write-combining; nt bypass hurt DRAM page locality).
__global__ __launch_bounds__(256, 3) void gemm2_kernel(
    const unsigned short* __restrict__ proj, const int* __restrict__ mask,
    float* __restrict__ out) {
    __shared__ unsigned short Qs[128 * 64];   // swizzled
    __shared__ unsigned short Ks[128 * 64];
    int bid = blockIdx.x;          // 144*16
    int batch = bid >> 4;
    int tl = bid & 15;
    int tm = tl >> 2, tn = tl & 3;
    int b = batch / 9, t = batch - b * 9;
    int tid = threadIdx.x, lane = tid & 63, wave = tid >> 6;
    int wm = (wave & 1) * 64, wn = (wave >> 1) * 64;
    int col_l = lane & 15;
    int qg = lane >> 4;
    size_t out_base = ((size_t)b * 9 + t) * 512 * 512;

    if (tm > tn) {
        // whole tile strictly below diagonal: |L|/8 error << threshold
#pragma unroll 4
        for (int r = 0; r < 128; r += 8) {
            int row = r + (tid >> 5);
            int c4 = (tid & 31) * 4;
            int gm = tm * 128 + row;
            int gn = tn * 128 + c4;
            int4 mi = *(const int4*)(mask + b * 512 + gn);
            f32x4 v;
            v[0] = (-(1.0f - (float)mi.x) * NEG_C - NEG_C) * 0.125f;
            v[1] = (-(1.0f - (float)mi.y) * NEG_C - NEG_C) * 0.125f;
            v[2] = (-(1.0f - (float)mi.z) * NEG_C - NEG_C) * 0.125f;
            v[3] = (-(1.0f - (float)mi.w) * NEG_C - NEG_C) * 0.125f;
            *(f32x4*)(out + out_base + (size_t)gm * 512 + gn) = v;
        }
        return;
    }

    const unsigned short* qbase = proj + (((size_t)(b * 512 + tm * 128) * 9) + t) * 128;
    const unsigned short* kbase = proj + (((size_t)(b * 512 + tn * 128) * 9) + t) * 128 + 64;
#pragma unroll
    for (int q = 0; q < 4; ++q) {
        int c = (wave * 4 + q) * 64 + lane;   // 0..1023
        int r = c >> 3;
        int g = (c & 7) ^ (r & 7);
        async_copy16(qbase + (size_t)r * 1152 + g * 8,
                     Qs + (size_t)(wave * 4 + q) * 512);
        async_copy16(kbase + (size_t)r * 1152 + g * 8,
                     Ks + (size_t)(wave * 4 + q) * 512);
    }
    __syncthreads();

    f32x4 acc[4][4] = {};                     // [i:n-block][j:m-block]
#pragma unroll
    for (int ks = 0; ks < 2; ++ks) {
        Frag qf[4], kf[4];
        int g = ks * 4 + qg;
#pragma unroll
        for (int i = 0; i < 4; ++i) {
            int rm = wm + i * 16 + col_l;
            int rn = wn + i * 16 + col_l;
            qf[i].i = *(const int4*)(Qs + rm * 64 + ((g ^ (rm & 7)) * 8));
            kf[i].i = *(const int4*)(Ks + rn * 64 + ((g ^ (rn & 7)) * 8));
        }
#pragma unroll
        for (int i = 0; i < 4; ++i)
#pragma unroll
            for (int j = 0; j < 4; ++j)
                acc[i][j] = __builtin_amdgcn_mfma_f32_16x16x32_bf16(
                    kf[i].b, qf[j].b, acc[i][j], 0, 0, 0);
    }

#pragma unroll
    for (int i = 0; i < 4; ++i) {
        int gn0 = tn * 128 + wn + i * 16 + qg * 4;   // %4==0
        int4 mi = *(const int4*)(mask + b * 512 + gn0);
#pragma unroll
        for (int j = 0; j < 4; ++j) {
            int gm = tm * 128 + wm + j * 16 + col_l;
            f32x4 v;
#pragma unroll
            for (int r = 0; r < 4; ++r) {
                float pm = (float)((&mi.x)[r]);
                float x = acc[i][j][r] * pm - (1.0f - pm) * NEG_C;
                if (gm > gn0 + r) x -= NEG_C;
                v[r] = x * 0.125f;
            }
            *(f32x4*)(out + out_base + (size_t)gm * 512 + gn0) = v;
        }
    }
}

// ---------------------------------------------------------------- launch
extern "C" void kernel_launch(void* const* d_in, const int* in_sizes, int n_in,
                              void* d_out, int out_size, void* d_ws, size_t ws_size,
                              hipStream_t stream) {
    const float* hidden = (const float*)d_in[0];   // [16][512][768]
    const float* W      = (const float*)d_in[1];   // [768][1152]
    const float* bias   = (const float*)d_in[2];   // [1152]
    const int*   mask   = (const int*)d_in[3];     // [16][512]
    float* out = (float*)d_out;                    // [16][9][512][512]

    char* ws = (char*)d_ws;
    unsigned short* Ah   = (unsigned short*)(ws);              // 8192*768  bf16
    unsigned short* WT   = (unsigned short*)(ws + 12582912);   // 1152*768  bf16
    unsigned short* proj = (unsigned short*)(ws + 14352384);   // 8192*1152 bf16

    prep_kernel<<<7008, 256, 0, stream>>>(W, WT, hidden, Ah);
    dim3 g1(9, 64);
    gemm1_kernel<<<g1, 256, 0, stream>>>(Ah, WT, bias, proj);
    gemm2_kernel<<<2304, 256, 0, stream>>>(proj, mask, out);
}